// Round 2
// baseline (204.895 us; speedup 1.0000x reference)
//
#include <hip/hip_runtime.h>
#include <stdint.h>

#define NN 8192
#define MM 16
#define FN 128
#define HH 512

typedef unsigned short u16;
typedef unsigned int u32;
typedef __bf16 bf16;
typedef __bf16 bf16x8 __attribute__((ext_vector_type(8)));
typedef float f32x4 __attribute__((ext_vector_type(4)));

// ---------------- runtime dtype probes ----------------
// flags[0] = 1 if float inputs are fp32 (else bf16)
// flags[1] = 1 if edge_fea_idx is int64 (else int32)
__global__ void detect_kernel(const u16* __restrict__ node,
                              const u32* __restrict__ idxw,
                              int* __restrict__ flags) {
  if (threadIdx.x == 0 && blockIdx.x == 0) {
    // bf16 N(0,1) data: even u16s have sane exponents (or zero).
    // fp32 data: even u16s are low mantissa halves -> uniform-random exponents.
    int insane = 0;
    for (int i = 0; i < 64; ++i) {
      int e = (node[2 * i] >> 7) & 0xFF;
      if (!(e == 0 || (e >= 90 && e <= 140))) ++insane;
    }
    flags[0] = (insane >= 8) ? 1 : 0;
    // int64 little-endian values in [0,8192): odd 32-bit words are all 0.
    // int32 data: odd words are random node ids, P(all 32 zero) ~ 8192^-32.
    int nz = 0;
    for (int i = 0; i < 32; ++i)
      if (idxw[2 * i + 1] != 0) ++nz;
    flags[1] = (nz == 0) ? 1 : 0;
  }
}

// d_is[i] = rsqrt(1 + #valid neighbors)
__global__ __launch_bounds__(256) void deg_kernel(const int* __restrict__ idx,
                                                  const int* __restrict__ flags,
                                                  float* __restrict__ dis) {
  int i = blockIdx.x * blockDim.x + threadIdx.x;
  if (i >= NN) return;
  const int sh = flags[1];  // int64 -> stride-2 over 32-bit words
  int c = 1;
#pragma unroll
  for (int e = 0; e < MM; ++e) c += (idx[(i * MM + e) << sh] >= 0) ? 1 : 0;
  dis[i] = rsqrtf((float)c);
}

// convert 4 bias vectors to canonical bf16 (concat layout: 4 x 512)
__global__ __launch_bounds__(256) void bias_kernel(
    const void* __restrict__ b0, const void* __restrict__ b1,
    const void* __restrict__ b2, const void* __restrict__ b3,
    const int* __restrict__ flags, u16* __restrict__ out) {
  int id = blockIdx.x * 256 + threadIdx.x;
  if (id >= 4 * HH) return;
  const void* src;
  switch (id >> 9) {
    case 0: src = b0; break;
    case 1: src = b1; break;
    case 2: src = b2; break;
    default: src = b3; break;
  }
  int off = id & (HH - 1);
  bf16 v = flags[0] ? (bf16)((const float*)src)[off] : ((const bf16*)src)[off];
  out[id] = *(u16*)&v;
}

// transpose weights (K x 512) -> canonical bf16 (512 x K)
__global__ __launch_bounds__(256) void transpose_all(
    const void* __restrict__ Wemb, const void* __restrict__ W1,
    const void* __restrict__ W2, const void* __restrict__ W3,
    const int* __restrict__ flags, u16* __restrict__ TWemb,
    u16* __restrict__ TW1, u16* __restrict__ TW2, u16* __restrict__ TW3) {
  const void* W;
  u16* T;
  int K;
  switch (blockIdx.z) {
    case 0: W = Wemb; T = TWemb; K = FN; break;
    case 1: W = W1; T = TW1; K = HH; break;
    case 2: W = W2; T = TW2; K = HH; break;
    default: W = W3; T = TW3; K = HH; break;
  }
  int k0 = blockIdx.x * 32;
  if (k0 >= K) return;
  int n0 = blockIdx.y * 32;
  const int f32 = flags[0];
  __shared__ u16 t[32][33];
  int tx = threadIdx.x & 31, ty = threadIdx.x >> 5;
#pragma unroll
  for (int r = ty; r < 32; r += 8) {
    size_t src = (size_t)(k0 + r) * HH + n0 + tx;
    bf16 v = f32 ? (bf16)((const float*)W)[src] : ((const bf16*)W)[src];
    t[r][tx] = *(u16*)&v;
  }
  __syncthreads();
#pragma unroll
  for (int r = ty; r < 32; r += 8) T[(size_t)(n0 + r) * K + k0 + tx] = t[tx][r];
}

// C(8192x512) = A(8192xK) @ Bt^T + bias.  Bt is canonical bf16 N x K.
// A is bf16, unless A_MAYBE_F32 && flags[0] (fp32 -> convert in staging).
// 128x128 tile, 4 waves (2x2), 16x16x32 bf16 MFMA 4x4/wave, BK=32,
// register staging + ds_write_b128 (correctness-first; no global_load_lds).
template <int K, bool RELU, bool FINAL, bool A_MAYBE_F32>
__global__ __launch_bounds__(256) void gemm_kernel(
    const void* __restrict__ A, const u16* __restrict__ Bt,
    const u16* __restrict__ bias, const int* __restrict__ flags,
    void* __restrict__ C) {
  __shared__ __align__(16) u16 As[128 * 32];  // [row][k]
  __shared__ __align__(16) u16 Bs[128 * 32];  // [n][k]
  const int rtile = blockIdx.x, ctile = blockIdx.y;
  const int tid = threadIdx.x;
  const int wave = tid >> 6, lane = tid & 63;
  const int wr = wave >> 1, wc = wave & 1;
  const int quad = lane >> 4, l16 = lane & 15;
  const int af32 = A_MAYBE_F32 ? flags[0] : 0;

  f32x4 acc[4][4] = {};

  const int srow = tid >> 2;  // 0..63 (plus +64 group)
  const int sseg = tid & 3;   // 16B segment within 64B row

  for (int k0 = 0; k0 < K; k0 += 32) {
    bf16x8 av0, av1, bv0, bv1;
    if (af32) {
      const float* Af = (const float*)A;
      const float* p0 = &Af[(size_t)(rtile * 128 + srow) * K + k0 + sseg * 8];
      const float* p1 = &Af[(size_t)(rtile * 128 + srow + 64) * K + k0 + sseg * 8];
      f32x4 x0 = *(const f32x4*)p0, x1 = *(const f32x4*)(p0 + 4);
      f32x4 y0 = *(const f32x4*)p1, y1 = *(const f32x4*)(p1 + 4);
#pragma unroll
      for (int t = 0; t < 4; ++t) {
        av0[t] = (bf16)x0[t];
        av0[4 + t] = (bf16)x1[t];
        av1[t] = (bf16)y0[t];
        av1[4 + t] = (bf16)y1[t];
      }
    } else {
      const u16* Ab = (const u16*)A;
      av0 = *(const bf16x8*)&Ab[(size_t)(rtile * 128 + srow) * K + k0 + sseg * 8];
      av1 = *(const bf16x8*)&Ab[(size_t)(rtile * 128 + srow + 64) * K + k0 + sseg * 8];
    }
    bv0 = *(const bf16x8*)&Bt[(size_t)(ctile * 128 + srow) * K + k0 + sseg * 8];
    bv1 = *(const bf16x8*)&Bt[(size_t)(ctile * 128 + srow + 64) * K + k0 + sseg * 8];

    __syncthreads();  // prev iter's LDS reads done before overwrite
    *(bf16x8*)&As[srow * 32 + sseg * 8] = av0;
    *(bf16x8*)&As[(srow + 64) * 32 + sseg * 8] = av1;
    *(bf16x8*)&Bs[srow * 32 + sseg * 8] = bv0;
    *(bf16x8*)&Bs[(srow + 64) * 32 + sseg * 8] = bv1;
    __syncthreads();

    bf16x8 afrag[4], bfrag[4];
#pragma unroll
    for (int i = 0; i < 4; ++i)
      afrag[i] = *(const bf16x8*)&As[(wr * 64 + i * 16 + l16) * 32 + quad * 8];
#pragma unroll
    for (int j = 0; j < 4; ++j)
      bfrag[j] = *(const bf16x8*)&Bs[(wc * 64 + j * 16 + l16) * 32 + quad * 8];
#pragma unroll
    for (int i = 0; i < 4; ++i)
#pragma unroll
      for (int j = 0; j < 4; ++j)
        acc[i][j] = __builtin_amdgcn_mfma_f32_16x16x32_bf16(afrag[i], bfrag[j],
                                                            acc[i][j], 0, 0, 0);
  }

  // C/D layout: col = lane&15, row = quad*4 + reg  (m89/m91)
  const int crow0 = rtile * 128 + wr * 64 + quad * 4;
  const int ccol0 = ctile * 128 + wc * 64 + l16;
  const int outf32 = FINAL ? flags[0] : 0;
#pragma unroll
  for (int j = 0; j < 4; ++j) {
    const int col = ccol0 + j * 16;
    const float bv = (float)(*(const bf16*)&bias[col]);
#pragma unroll
    for (int i = 0; i < 4; ++i) {
#pragma unroll
      for (int r = 0; r < 4; ++r) {
        float v = acc[i][j][r] + bv;
        if (RELU) v = fmaxf(v, 0.0f);
        size_t off = (size_t)(crow0 + i * 16 + r) * HH + col;
        if (FINAL && outf32) {
          ((float*)C)[off] = v;
        } else {
          bf16 o = (bf16)v;
          ((u16*)C)[off] = *(u16*)&o;
        }
      }
    }
  }
}

// y[i,:] = d[i] * ( d[i]*x[i,:] + sum_e d[j_e]*x[j_e,:] )   (wave per node)
__global__ __launch_bounds__(256) void agg_kernel(const u16* __restrict__ x,
                                                  const int* __restrict__ idx,
                                                  const int* __restrict__ flags,
                                                  const float* __restrict__ dis,
                                                  u16* __restrict__ y) {
  const int node = blockIdx.x * 4 + (threadIdx.x >> 6);
  const int lane = threadIdx.x & 63;
  const int c0 = lane * 8;
  const int sh = flags[1];
  const float wi = dis[node];
  float acc[8];
  bf16x8 xs = *(const bf16x8*)&x[(size_t)node * HH + c0];
#pragma unroll
  for (int t = 0; t < 8; ++t) acc[t] = wi * wi * (float)xs[t];
#pragma unroll
  for (int e = 0; e < MM; ++e) {
    const int j = idx[(node * MM + e) << sh];
    if (j >= 0) {
      const float w = wi * dis[j];
      bf16x8 v = *(const bf16x8*)&x[(size_t)j * HH + c0];
#pragma unroll
      for (int t = 0; t < 8; ++t) acc[t] += w * (float)v[t];
    }
  }
  bf16x8 o;
#pragma unroll
  for (int t = 0; t < 8; ++t) o[t] = (bf16)acc[t];
  *(bf16x8*)&y[(size_t)node * HH + c0] = o;
}

extern "C" void kernel_launch(void* const* d_in, const int* in_sizes, int n_in,
                              void* d_out, int out_size, void* d_ws, size_t ws_size,
                              hipStream_t stream) {
  const void* node = d_in[0];
  const int* idx = (const int*)d_in[1];
  const void* Wemb = d_in[2];
  const void* bemb = d_in[3];
  const void* W1 = d_in[4];
  const void* b1 = d_in[5];
  const void* W2 = d_in[6];
  const void* b2 = d_in[7];
  const void* W3 = d_in[8];
  const void* b3 = d_in[9];

  // workspace layout (~9.7 MB total; d_out doubles as bf16 ping buffer)
  char* p = (char*)d_ws;
  int* flags = (int*)p;      p += 256;
  float* dis = (float*)p;    p += NN * sizeof(float);       // 32 KB
  u16* biasBF = (u16*)p;     p += 4 * HH * sizeof(u16);     // 4 KB
  u16* TWemb = (u16*)p;      p += (size_t)HH * FN * 2;      // 128 KB
  u16* TW1 = (u16*)p;        p += (size_t)HH * HH * 2;      // 512 KB
  u16* TW2 = (u16*)p;        p += (size_t)HH * HH * 2;
  u16* TW3 = (u16*)p;        p += (size_t)HH * HH * 2;
  u16* xA = (u16*)p;         p += (size_t)NN * HH * 2;      // 8 MB
  u16* xO = (u16*)d_out;     // bf16 intermediate ping buffer

  detect_kernel<<<1, 64, 0, stream>>>((const u16*)node, (const u32*)idx, flags);
  deg_kernel<<<NN / 256, 256, 0, stream>>>(idx, flags, dis);
  bias_kernel<<<8, 256, 0, stream>>>(bemb, b1, b2, b3, flags, biasBF);
  transpose_all<<<dim3(16, 16, 4), 256, 0, stream>>>(Wemb, W1, W2, W3, flags,
                                                     TWemb, TW1, TW2, TW3);
  // x0 -> d_out, then ping-pong d_out <-> xA; final gemm writes d_out
  gemm_kernel<FN, false, false, true>
      <<<dim3(64, 4), 256, 0, stream>>>(node, TWemb, biasBF, flags, xO);
  agg_kernel<<<NN / 4, 256, 0, stream>>>(xO, idx, flags, dis, xA);
  gemm_kernel<HH, true, false, false>
      <<<dim3(64, 4), 256, 0, stream>>>(xA, TW1, biasBF + HH, flags, xO);
  agg_kernel<<<NN / 4, 256, 0, stream>>>(xO, idx, flags, dis, xA);
  gemm_kernel<HH, true, false, false>
      <<<dim3(64, 4), 256, 0, stream>>>(xA, TW2, biasBF + 2 * HH, flags, xO);
  agg_kernel<<<NN / 4, 256, 0, stream>>>(xO, idx, flags, dis, xA);
  gemm_kernel<HH, false, true, false>
      <<<dim3(64, 4), 256, 0, stream>>>(xA, TW3, biasBF + 3 * HH, flags, d_out);
}